// Round 7
// baseline (290.499 us; speedup 1.0000x reference)
//
#include <hip/hip_runtime.h>
#include <math.h>

#define BATCH 512
#define SEQ   256
#define DIM   256
#define NHEAD 8
#define DFF   1024
#define NT    1024
#define NWAVE 16

// ---------- helpers ----------

__device__ __forceinline__ float dot4f(float4 a, float4 b) {
  return fmaf(a.x, b.x, fmaf(a.y, b.y, fmaf(a.z, b.z, a.w * b.w)));
}

__device__ __forceinline__ float wave_allred(float v) {
  #pragma unroll
  for (int off = 32; off > 0; off >>= 1) v += __shfl_xor(v, off, 64);
  return v;
}

// 4-step reduce across the 16 kj-lanes
__device__ __forceinline__ float red16(float v) {
  v += __shfl_xor(v, 1, 16);
  v += __shfl_xor(v, 2, 16);
  v += __shfl_xor(v, 4, 16);
  v += __shfl_xor(v, 8, 16);
  return v;
}

// per-half (batch) block sum; ALL 1024 threads must call
__device__ __forceinline__ float half_sum(float v, float* red) {
  const int tid = threadIdx.x;
  v = wave_allred(v);
  __syncthreads();
  if ((tid & 63) == 0) red[tid >> 6] = v;
  __syncthreads();
  const int base = (tid >= 512) ? 8 : 0;
  float s = 0.f;
  #pragma unroll
  for (int i = 0; i < 8; ++i) s += red[base + i];
  return s;
}

struct XReg { float4 v[4]; };

__device__ __forceinline__ void load_xreg(const float* __restrict__ x, int kj, XReg& xr) {
  #pragma unroll
  for (int i = 0; i < 4; ++i) xr.v[i] = *(const float4*)(x + 4 * kj + 64 * i);
}

// one 256-row GEMV pass over this thread's K-slice; rows r = slot + 64m
__device__ __forceinline__ void gemv_pass(const float* __restrict__ W, int ldw, int koff,
                                          int slot, int kj,
                                          const XReg& x0, const XReg& x1,
                                          float acc[4][2]) {
  #pragma unroll
  for (int mp = 0; mp < 2; ++mp) {             // m-pairs: 8 loads in flight
    float4 w[2][4];
    #pragma unroll
    for (int mm = 0; mm < 2; ++mm) {
      const float* wr = W + (size_t)(slot + 64 * (2 * mp + mm)) * ldw + koff + 4 * kj;
      #pragma unroll
      for (int i = 0; i < 4; ++i) w[mm][i] = *(const float4*)(wr + 64 * i);
    }
    #pragma unroll
    for (int mm = 0; mm < 2; ++mm) {
      float a0 = 0.f, a1 = 0.f;
      #pragma unroll
      for (int i = 0; i < 4; ++i) {
        a0 += dot4f(w[mm][i], x0.v[i]);
        a1 += dot4f(w[mm][i], x1.v[i]);
      }
      acc[2 * mp + mm][0] += a0;
      acc[2 * mp + mm][1] += a1;
    }
  }
}

struct BatchBuf {
  float sc[2048];     // w~ [d][h] -> scores [h][s] -> att [s][h] -> u [h][d] -> ffb -> z1/a0/a1
  float pe[SEQ];
  float srcl[DIM];
  float qv[DIM];      // q -> tv(LN1) -> tv(LN2)
  float ao[DIM];
  float h1[DIM];      // h1 -> d1
  float h2[DIM];
  float xr[DIM];
  float znin[260];
  float fa[280];
  float znv[20];
  float cb[8];
  float scA[9 * 8];
  float scZ[20 * 8];
  float mHJ[8 * 8];
  float biasO8[8];
  float wsum8[8];
  float attA[8 * 9];
  float attZ[8 * 20];
  float oAcc[8 * 7];
  float peAcc8[8];
  int   Xa[SEQ];
  int   Xz[SEQ];
  float Xo[SEQ * 7];
};

// ---------- fused kernel: TWO batch elements per block ----------
// __launch_bounds__(NT, 4): 4 waves/EU min = 1 block/CU -> VGPR cap ~128, no spill.
// (Round 5 omitted the 2nd arg -> compiler capped VGPR=64 and spilled ~1KB/thread:
//  WRITE_SIZE 258MB, FETCH 232MB of scratch traffic.)

__global__ __launch_bounds__(NT, 4) void nmstpp_fused(
    const int*   __restrict__ X,
    const float* __restrict__ emb_act,
    const float* __restrict__ emb_zone,
    const float* __restrict__ lin0_w,
    const float* __restrict__ lin0_b,
    const float* __restrict__ qkv_w,
    const float* __restrict__ qkv_b,
    const float* __restrict__ attn_o_w,
    const float* __restrict__ attn_o_b,
    const float* __restrict__ ln1_g, const float* __restrict__ ln1_b,
    const float* __restrict__ ff1_w,
    const float* __restrict__ ff1_b,
    const float* __restrict__ ff2_w,
    const float* __restrict__ ff2_b,
    const float* __restrict__ ln2_g, const float* __restrict__ ln2_b,
    const float* __restrict__ relu_w,
    const float* __restrict__ relu_b,
    const float* __restrict__ dT_w,
    const float* __restrict__ dT_b,
    const float* __restrict__ lindT_w,
    const float* __restrict__ lindT_b,
    const float* __restrict__ zn_w,
    const float* __restrict__ zn_b,
    const float* __restrict__ linzn_w,
    const float* __restrict__ linzn_b,
    const float* __restrict__ act0_w,
    const float* __restrict__ act0_b,
    const float* __restrict__ act1_w,
    const float* __restrict__ act1_b,
    const float* __restrict__ linact_w,
    const float* __restrict__ linact_b,
    float* __restrict__ out)
{
  const int tid   = threadIdx.x;
  const int wid   = tid >> 6;
  const int lane  = tid & 63;
  const int batch = tid >> 9;        // 0 or 1 (half-block)
  const int tp    = tid & 511;       // index within half
  const int b     = 2 * blockIdx.x + batch;
  const int kj    = tid & 15;        // K-split lane
  const int slot  = tid >> 4;        // row slot [0,64)

  __shared__ alignas(16) BatchBuf bb[2];
  __shared__ float embA[9 * 65];
  __shared__ float embZ[20 * 65];
  __shared__ float l0w[128 * 7];
  __shared__ float l0b[128];
  __shared__ float red[NWAVE];

  BatchBuf* mb = &bb[batch];
  float* sc0 = bb[0].sc;
  float* sc1 = bb[1].sc;

  // ---- phase 0: stage shared tables + per-batch X / pe ----
  for (int i = tid; i < 9 * 64;  i += NT) embA[(i >> 6) * 65 + (i & 63)] = emb_act[i];
  for (int i = tid; i < 20 * 64; i += NT) embZ[(i >> 6) * 65 + (i & 63)] = emb_zone[i];
  for (int i = tid; i < 128 * 7; i += NT) l0w[i] = lin0_w[i];
  if (tid < 128) l0b[tid] = lin0_b[tid];
  if (tp < SEQ) {
    const int* xrow = X + (b * SEQ + tp) * 9;
    mb->Xa[tp] = xrow[0];
    mb->Xz[tp] = xrow[1];
    #pragma unroll
    for (int j = 0; j < 7; ++j) mb->Xo[tp * 7 + j] = (float)xrow[2 + j];
    float ex  = (float)(2 * tp) / (float)SEQ;
    float ang = (float)b * exp2f(-ex * 6.643856189774724f);  // 100^-ex
    mb->pe[tp] = ((tp & 1) == 0) ? sinf(ang) : cosf(ang);
  }
  __syncthreads();

  // ---- phase 1: src at last position ----
  if (tp < DIM) {
    int av = mb->Xa[SEQ - 1], zv = mb->Xz[SEQ - 1];
    float v;
    if (tp < 64)        v = embA[av * 65 + tp];
    else if (tp < 128)  v = embZ[zv * 65 + (tp - 64)];
    else {
      const float* lr = l0w + (tp - 128) * 7;
      float acc = l0b[tp - 128];
      #pragma unroll
      for (int j = 0; j < 7; ++j) acc = fmaf(lr[j], mb->Xo[(SEQ - 1) * 7 + j], acc);
      v = acc;
    }
    mb->srcl[tp] = v + mb->pe[SEQ - 1];
  }
  __syncthreads();

  // ---- phase 2: q = Wq @ srcl + bq (16-lane K-split, 4 rows/thread) ----
  {
    XReg x0, x1;
    load_xreg(bb[0].srcl, kj, x0);
    load_xreg(bb[1].srcl, kj, x1);
    float acc[4][2] = {};
    gemv_pass(qkv_w, 256, 0, slot, kj, x0, x1, acc);
    #pragma unroll
    for (int m = 0; m < 4; ++m) {
      float s0 = red16(acc[m][0]);
      float s1 = red16(acc[m][1]);
      if (kj == 0) {
        int r = slot + 64 * m;
        float bv = qkv_b[r];
        bb[0].qv[r] = s0 + bv;
        bb[1].qv[r] = s1 + bv;
      }
    }
  }
  __syncthreads();

  // ---- phase 3: w~[d][h] (coalesced column sweep; each half does its batch) ----
  {
    const float inv = 0.17677669529663687f;  // 1/sqrt(32)
    const int d = tp & 255;
    const int hbase = (tp < 256) ? 0 : 4;
    float acc[4] = {0.f, 0.f, 0.f, 0.f};
    for (int c = 0; c < 32; ++c) {
      #pragma unroll
      for (int hh = 0; hh < 4; ++hh) {
        int h = hbase + hh;
        acc[hh] = fmaf(mb->qv[h * 32 + c], qkv_w[(DIM + h * 32 + c) * DIM + d], acc[hh]);
      }
    }
    #pragma unroll
    for (int hh = 0; hh < 4; ++hh) mb->sc[d * 8 + hbase + hh] = acc[hh] * inv;
  }
  __syncthreads();

  // ---- phase 3.5: collapse scores into lookup tables ----
  {
    if (tp < 296) {
      int h = tp / 37, k = tp - h * 37;
      if (k < 9) {
        float acc = 0.f;
        for (int c = 0; c < 64; ++c) acc = fmaf(mb->sc[c * 8 + h], embA[k * 65 + c], acc);
        mb->scA[k * 8 + h] = acc;
      } else if (k < 29) {
        int z = k - 9; float acc = 0.f;
        for (int c = 0; c < 64; ++c) acc = fmaf(mb->sc[(64 + c) * 8 + h], embZ[z * 65 + c], acc);
        mb->scZ[z * 8 + h] = acc;
      } else if (k < 36) {
        int j = k - 29; float acc = 0.f;
        for (int kk = 0; kk < 128; ++kk) acc = fmaf(mb->sc[(128 + kk) * 8 + h], l0w[kk * 7 + j], acc);
        mb->mHJ[h * 8 + j] = acc;
      } else {
        float acc = 0.f;
        for (int c = 0; c < 256; ++c) acc += mb->sc[c * 8 + h];
        mb->wsum8[h] = acc;
      }
    } else if (tp < 304) {
      int h = tp - 296; float acc = 0.f;
      for (int kk = 0; kk < 128; ++kk) acc = fmaf(mb->sc[(128 + kk) * 8 + h], l0b[kk], acc);
      mb->biasO8[h] = acc;
    } else if (tp < 312) {
      int h = tp - 304; float acc = 0.f;
      for (int c = 0; c < 32; ++c) acc += mb->qv[h * 32 + c] * qkv_b[DIM + h * 32 + c];
      mb->cb[h] = acc * 0.17677669529663687f;
    }
  }
  __syncthreads();

  // ---- phase 4: scores via tables (thread = position) ----
  if (tp < SEQ) {
    const int s = tp;
    int av = mb->Xa[s], zv = mb->Xz[s];
    float o[7];
    #pragma unroll
    for (int j = 0; j < 7; ++j) o[j] = mb->Xo[s * 7 + j];
    float pes = mb->pe[s];
    #pragma unroll
    for (int h = 0; h < NHEAD; ++h) {
      float acc = mb->scA[av * 8 + h] + mb->scZ[zv * 8 + h] + mb->biasO8[h] + mb->cb[h];
      acc = fmaf(pes, mb->wsum8[h], acc);
      #pragma unroll
      for (int j = 0; j < 7; ++j) acc = fmaf(mb->mHJ[h * 8 + j], o[j], acc);
      mb->sc[h * SEQ + s] = acc;
    }
  }
  __syncthreads();

  // ---- phase 5: softmax per head, in-place transpose (reg-staged) ----
  {
    float vals[8]; float rinv = 0.f;
    int h = tp >> 5, idx = tp & 31;
    if (tp < 256) {
      float m = -1e30f;
      #pragma unroll
      for (int i = 0; i < 8; ++i) {
        vals[i] = mb->sc[h * SEQ + idx * 8 + i];
        m = fmaxf(m, vals[i]);
      }
      #pragma unroll
      for (int off = 16; off > 0; off >>= 1) m = fmaxf(m, __shfl_xor(m, off, 32));
      float lsum = 0.f;
      #pragma unroll
      for (int i = 0; i < 8; ++i) { vals[i] = expf(vals[i] - m); lsum += vals[i]; }
      #pragma unroll
      for (int off = 16; off > 0; off >>= 1) lsum += __shfl_xor(lsum, off, 32);
      rinv = 1.0f / lsum;
    }
    __syncthreads();
    if (tp < 256) {
      #pragma unroll
      for (int i = 0; i < 8; ++i) mb->sc[(idx * 8 + i) * 8 + h] = vals[i] * rinv;
    }
  }
  __syncthreads();

  // ---- phase 6a: attention-weighted histograms / moments ----
  if (tp < 296) {
    int h = tp / 37, k = tp - h * 37;
    float acc = 0.f;
    if (k < 29) {
      int mybin = (k < 9) ? k : (k - 9);
      const int* bins = (k < 9) ? mb->Xa : mb->Xz;
      for (int s = 0; s < SEQ; ++s) {
        float at = mb->sc[s * 8 + h];
        acc += (bins[s] == mybin) ? at : 0.f;
      }
      if (k < 9) mb->attA[h * 9 + k] = acc; else mb->attZ[h * 20 + (k - 9)] = acc;
    } else if (k < 36) {
      int j = k - 29;
      for (int s = 0; s < SEQ; ++s) acc = fmaf(mb->sc[s * 8 + h], mb->Xo[s * 7 + j], acc);
      mb->oAcc[h * 7 + j] = acc;
    } else {
      for (int s = 0; s < SEQ; ++s) acc = fmaf(mb->sc[s * 8 + h], mb->pe[s], acc);
      mb->peAcc8[h] = acc;
    }
  }
  __syncthreads();

  // ---- phase 6b: reconstruct u[h][d] (overwrites att) ----
  if (tp < DIM) {
    float acc[NHEAD];
    #pragma unroll
    for (int h = 0; h < NHEAD; ++h) acc[h] = mb->peAcc8[h];
    if (tp < 64) {
      for (int a = 0; a < 9; ++a) {
        float ev = embA[a * 65 + tp];
        #pragma unroll
        for (int h = 0; h < NHEAD; ++h) acc[h] = fmaf(mb->attA[h * 9 + a], ev, acc[h]);
      }
    } else if (tp < 128) {
      int d = tp - 64;
      for (int z = 0; z < 20; ++z) {
        float ev = embZ[z * 65 + d];
        #pragma unroll
        for (int h = 0; h < NHEAD; ++h) acc[h] = fmaf(mb->attZ[h * 20 + z], ev, acc[h]);
      }
    } else {
      int kk = tp - 128;
      #pragma unroll
      for (int j = 0; j < 7; ++j) {
        float ov = l0w[kk * 7 + j];
        #pragma unroll
        for (int h = 0; h < NHEAD; ++h) acc[h] = fmaf(mb->oAcc[h * 7 + j], ov, acc[h]);
      }
      #pragma unroll
      for (int h = 0; h < NHEAD; ++h) acc[h] += l0b[kk];
    }
    #pragma unroll
    for (int h = 0; h < NHEAD; ++h) mb->sc[h * DIM + tp] = acc[h];
  }
  __syncthreads();

  // ---- phase 7: ao = Wv @ u + bv (head-grouped rows so x is per-thread fixed) ----
  {
    const int h = slot >> 3;
    const int rbase = h * 32 + (slot & 7);
    XReg x0, x1;
    load_xreg(sc0 + h * DIM, kj, x0);
    load_xreg(sc1 + h * DIM, kj, x1);
    #pragma unroll
    for (int mp = 0; mp < 2; ++mp) {
      float4 w[2][4];
      #pragma unroll
      for (int mm = 0; mm < 2; ++mm) {
        int r = rbase + 8 * (2 * mp + mm);
        const float* wr = qkv_w + (size_t)(2 * DIM + r) * DIM + 4 * kj;
        #pragma unroll
        for (int i = 0; i < 4; ++i) w[mm][i] = *(const float4*)(wr + 64 * i);
      }
      #pragma unroll
      for (int mm = 0; mm < 2; ++mm) {
        float a0 = 0.f, a1 = 0.f;
        #pragma unroll
        for (int i = 0; i < 4; ++i) {
          a0 += dot4f(w[mm][i], x0.v[i]);
          a1 += dot4f(w[mm][i], x1.v[i]);
        }
        a0 = red16(a0); a1 = red16(a1);
        if (kj == 0) {
          int r = rbase + 8 * (2 * mp + mm);
          float bv = qkv_b[2 * DIM + r];
          bb[0].ao[r] = bv + a0;
          bb[1].ao[r] = bv + a1;
        }
      }
    }
  }
  __syncthreads();

  // ---- phase 8: tv = srcl + attn_o(ao); h1 = LN1(tv) ----
  {
    XReg x0, x1;
    load_xreg(bb[0].ao, kj, x0);
    load_xreg(bb[1].ao, kj, x1);
    float acc[4][2] = {};
    gemv_pass(attn_o_w, 256, 0, slot, kj, x0, x1, acc);
    #pragma unroll
    for (int m = 0; m < 4; ++m) {
      float s0 = red16(acc[m][0]);
      float s1 = red16(acc[m][1]);
      if (kj == 0) {
        int r = slot + 64 * m;
        float bv = attn_o_b[r];
        bb[0].qv[r] = bb[0].srcl[r] + bv + s0;
        bb[1].qv[r] = bb[1].srcl[r] + bv + s1;
      }
    }
  }
  __syncthreads();
  {
    float tv = (tp < DIM) ? mb->qv[tp] : 0.f;
    float mean = half_sum(tv, red) * (1.0f / 256.0f);
    float dv = (tp < DIM) ? (tv - mean) : 0.f;
    float var = half_sum(dv * dv, red) * (1.0f / 256.0f);
    if (tp < DIM) mb->h1[tp] = dv / sqrtf(var + 1e-5f) * ln1_g[tp] + ln1_b[tp];
  }
  __syncthreads();

  // ---- phase 9: ffb = relu(ff1 @ h1 + b) (4 row-passes) ----
  {
    XReg x0, x1;
    load_xreg(bb[0].h1, kj, x0);
    load_xreg(bb[1].h1, kj, x1);
    #pragma unroll
    for (int p = 0; p < 4; ++p) {
      float acc[4][2] = {};
      gemv_pass(ff1_w + (size_t)(256 * p) * 256, 256, 0, slot, kj, x0, x1, acc);
      #pragma unroll
      for (int m = 0; m < 4; ++m) {
        float s0 = red16(acc[m][0]);
        float s1 = red16(acc[m][1]);
        if (kj == 0) {
          int r = 256 * p + slot + 64 * m;
          float bv = ff1_b[r];
          sc0[r] = fmaxf(s0 + bv, 0.f);
          sc1[r] = fmaxf(s1 + bv, 0.f);
        }
      }
    }
  }
  __syncthreads();

  // ---- phase 10: tv = h1 + ff2 @ ffb + b; h2 = LN2(tv) (4 K-passes) ----
  {
    float acc[4][2] = {};
    #pragma unroll
    for (int p = 0; p < 4; ++p) {
      XReg x0, x1;
      load_xreg(sc0 + 256 * p, kj, x0);
      load_xreg(sc1 + 256 * p, kj, x1);
      gemv_pass(ff2_w, 1024, 256 * p, slot, kj, x0, x1, acc);
    }
    #pragma unroll
    for (int m = 0; m < 4; ++m) {
      float s0 = red16(acc[m][0]);
      float s1 = red16(acc[m][1]);
      if (kj == 0) {
        int r = slot + 64 * m;
        float bv = ff2_b[r];
        bb[0].qv[r] = bb[0].h1[r] + bv + s0;
        bb[1].qv[r] = bb[1].h1[r] + bv + s1;
      }
    }
  }
  __syncthreads();
  {
    float tv = (tp < DIM) ? mb->qv[tp] : 0.f;
    float mean = half_sum(tv, red) * (1.0f / 256.0f);
    float dv = (tp < DIM) ? (tv - mean) : 0.f;
    float var = half_sum(dv * dv, red) * (1.0f / 256.0f);
    if (tp < DIM) mb->h2[tp] = dv / sqrtf(var + 1e-5f) * ln2_g[tp] + ln2_b[tp];
  }
  __syncthreads();

  // ---- phase 11: xr = relu_w @ h2 + b ----
  {
    XReg x0, x1;
    load_xreg(bb[0].h2, kj, x0);
    load_xreg(bb[1].h2, kj, x1);
    float acc[4][2] = {};
    gemv_pass(relu_w, 256, 0, slot, kj, x0, x1, acc);
    #pragma unroll
    for (int m = 0; m < 4; ++m) {
      float s0 = red16(acc[m][0]);
      float s1 = red16(acc[m][1]);
      if (kj == 0) {
        int r = slot + 64 * m;
        float bv = relu_b[r];
        bb[0].xr[r] = bv + s0;
        bb[1].xr[r] = bv + s1;
      }
    }
  }
  __syncthreads();

  // ---- phase 12: d1 = dT_w @ xr + b; dT = lindT . d1 + b ----
  {
    XReg x0, x1;
    load_xreg(bb[0].xr, kj, x0);
    load_xreg(bb[1].xr, kj, x1);
    float acc[4][2] = {};
    gemv_pass(dT_w, 256, 0, slot, kj, x0, x1, acc);
    #pragma unroll
    for (int m = 0; m < 4; ++m) {
      float s0 = red16(acc[m][0]);
      float s1 = red16(acc[m][1]);
      if (kj == 0) {
        int r = slot + 64 * m;
        float bv = dT_b[r];
        bb[0].h1[r] = bv + s0;               // h1 = d1
        bb[1].h1[r] = bv + s1;
      }
    }
  }
  __syncthreads();
  float dTv;
  {
    float v = (tp < DIM) ? lindT_w[tp] * mb->h1[tp] : 0.f;
    dTv = half_sum(v, red) + lindT_b[0];
  }

  // ---- phase 13: zn path (row pairs, wave-per-pair) ----
  if (tp < DIM) { mb->znin[1 + tp] = mb->xr[tp]; mb->fa[21 + tp] = mb->xr[tp]; }
  if (tp == 0)  { mb->znin[0] = dTv; mb->fa[20] = dTv; }
  __syncthreads();
  float* z1_0 = sc0 + 1024; float* z1_1 = sc1 + 1024;
  for (int r0 = 2 * wid; r0 < 257; r0 += 32) {
    int r1 = r0 + 1;
    bool has2 = (r1 < 257);
    const float* wa = zn_w + (size_t)r0 * 257;
    const float* wb = zn_w + (size_t)r1 * 257;
    float pa0 = 0.f, pa1 = 0.f, pb0 = 0.f, pb1 = 0.f;
    for (int j = lane; j < 257; j += 64) {
      float xa = bb[0].znin[j], xb = bb[1].znin[j];
      float w0 = wa[j];
      pa0 = fmaf(w0, xa, pa0); pa1 = fmaf(w0, xb, pa1);
      if (has2) { float w1 = wb[j]; pb0 = fmaf(w1, xa, pb0); pb1 = fmaf(w1, xb, pb1); }
    }
    pa0 = wave_allred(pa0); pa1 = wave_allred(pa1);
    pb0 = wave_allred(pb0); pb1 = wave_allred(pb1);
    if (lane == 0) {
      z1_0[r0] = zn_b[r0] + pa0; z1_1[r0] = zn_b[r0] + pa1;
      if (has2) { z1_0[r1] = zn_b[r1] + pb0; z1_1[r1] = zn_b[r1] + pb1; }
    }
  }
  __syncthreads();
  for (int r0 = 2 * wid; r0 < 20; r0 += 32) {
    int r1 = r0 + 1;
    const float* wa = linzn_w + (size_t)r0 * 257;
    const float* wb = linzn_w + (size_t)r1 * 257;
    float pa0 = 0.f, pa1 = 0.f, pb0 = 0.f, pb1 = 0.f;
    for (int j = lane; j < 257; j += 64) {
      float x0v = z1_0[j], x1v = z1_1[j];
      float w0 = wa[j], w1 = wb[j];
      pa0 = fmaf(w0, x0v, pa0); pa1 = fmaf(w0, x1v, pa1);
      pb0 = fmaf(w1, x0v, pb0); pb1 = fmaf(w1, x1v, pb1);
    }
    pa0 = wave_allred(pa0); pa1 = wave_allred(pa1);
    pb0 = wave_allred(pb0); pb1 = wave_allred(pb1);
    if (lane == 0) {
      bb[0].znv[r0] = linzn_b[r0] + pa0; bb[0].fa[r0] = linzn_b[r0] + pa0;
      bb[1].znv[r0] = linzn_b[r0] + pa1; bb[1].fa[r0] = linzn_b[r0] + pa1;
      bb[0].znv[r1] = linzn_b[r1] + pb0; bb[0].fa[r1] = linzn_b[r1] + pb0;
      bb[1].znv[r1] = linzn_b[r1] + pb1; bb[1].fa[r1] = linzn_b[r1] + pb1;
    }
  }
  __syncthreads();

  // ---- phase 14: ac = linact @ act1 @ act0 @ fa (row pairs) ----
  float* a0_0 = sc0 + 1312; float* a0_1 = sc1 + 1312;
  for (int r0 = 2 * wid; r0 < 277; r0 += 32) {
    int r1 = r0 + 1;
    bool has2 = (r1 < 277);
    const float* wa = act0_w + (size_t)r0 * 277;
    const float* wb = act0_w + (size_t)r1 * 277;
    float pa0 = 0.f, pa1 = 0.f, pb0 = 0.f, pb1 = 0.f;
    for (int j = lane; j < 277; j += 64) {
      float xa = bb[0].fa[j], xb = bb[1].fa[j];
      float w0 = wa[j];
      pa0 = fmaf(w0, xa, pa0); pa1 = fmaf(w0, xb, pa1);
      if (has2) { float w1 = wb[j]; pb0 = fmaf(w1, xa, pb0); pb1 = fmaf(w1, xb, pb1); }
    }
    pa0 = wave_allred(pa0); pa1 = wave_allred(pa1);
    pb0 = wave_allred(pb0); pb1 = wave_allred(pb1);
    if (lane == 0) {
      a0_0[r0] = act0_b[r0] + pa0; a0_1[r0] = act0_b[r0] + pa1;
      if (has2) { a0_0[r1] = act0_b[r1] + pb0; a0_1[r1] = act0_b[r1] + pb1; }
    }
  }
  __syncthreads();
  float* a1_0 = sc0 + 1024; float* a1_1 = sc1 + 1024;  // z1 dead
  for (int r0 = 2 * wid; r0 < 277; r0 += 32) {
    int r1 = r0 + 1;
    bool has2 = (r1 < 277);
    const float* wa = act1_w + (size_t)r0 * 277;
    const float* wb = act1_w + (size_t)r1 * 277;
    float pa0 = 0.f, pa1 = 0.f, pb0 = 0.f, pb1 = 0.f;
    for (int j = lane; j < 277; j += 64) {
      float xa = a0_0[j], xb = a0_1[j];
      float w0 = wa[j];
      pa0 = fmaf(w0, xa, pa0); pa1 = fmaf(w0, xb, pa1);
      if (has2) { float w1 = wb[j]; pb0 = fmaf(w1, xa, pb0); pb1 = fmaf(w1, xb, pb1); }
    }
    pa0 = wave_allred(pa0); pa1 = wave_allred(pa1);
    pb0 = wave_allred(pb0); pb1 = wave_allred(pb1);
    if (lane == 0) {
      a1_0[r0] = act1_b[r0] + pa0; a1_1[r0] = act1_b[r0] + pa1;
      if (has2) { a1_0[r1] = act1_b[r1] + pb0; a1_1[r1] = act1_b[r1] + pb1; }
    }
  }
  __syncthreads();

  // ---- phase 15: outputs ----
  for (int r = wid; r < 5; r += 16) {
    const float* wr = linact_w + (size_t)r * 277;
    float p0 = 0.f, p1 = 0.f;
    for (int j = lane; j < 277; j += 64) {
      float w = wr[j];
      p0 = fmaf(w, a1_0[j], p0);
      p1 = fmaf(w, a1_1[j], p1);
    }
    p0 = wave_allred(p0); p1 = wave_allred(p1);
    if (lane == 0) {
      out[(2 * blockIdx.x)     * 26 + 21 + r] = linact_b[r] + p0;
      out[(2 * blockIdx.x + 1) * 26 + 21 + r] = linact_b[r] + p1;
    }
  }
  if (tp == 0) out[b * 26] = dTv;
  if (tp < 20) out[b * 26 + 1 + tp] = mb->znv[tp];
}

// ---------- launcher ----------

extern "C" void kernel_launch(void* const* d_in, const int* in_sizes, int n_in,
                              void* d_out, int out_size, void* d_ws, size_t ws_size,
                              hipStream_t stream) {
  (void)in_sizes; (void)n_in; (void)d_ws; (void)ws_size; (void)out_size;
  const int*   X        = (const int*)  d_in[0];
  const float* emb_act  = (const float*)d_in[1];
  const float* emb_zone = (const float*)d_in[2];
  const float* lin0_w   = (const float*)d_in[3];
  const float* lin0_b   = (const float*)d_in[4];
  const float* qkv_w    = (const float*)d_in[5];
  const float* qkv_b    = (const float*)d_in[6];
  const float* attn_o_w = (const float*)d_in[7];
  const float* attn_o_b = (const float*)d_in[8];
  const float* ln1_g    = (const float*)d_in[9];
  const float* ln1_b    = (const float*)d_in[10];
  const float* ff1_w    = (const float*)d_in[11];
  const float* ff1_b    = (const float*)d_in[12];
  const float* ff2_w    = (const float*)d_in[13];
  const float* ff2_b    = (const float*)d_in[14];
  const float* ln2_g    = (const float*)d_in[15];
  const float* ln2_b    = (const float*)d_in[16];
  const float* relu_w   = (const float*)d_in[17];
  const float* relu_b   = (const float*)d_in[18];
  const float* dT_w     = (const float*)d_in[19];
  const float* dT_b     = (const float*)d_in[20];
  const float* lindT_w  = (const float*)d_in[21];
  const float* lindT_b  = (const float*)d_in[22];
  const float* zn_w     = (const float*)d_in[23];
  const float* zn_b     = (const float*)d_in[24];
  const float* linzn_w  = (const float*)d_in[25];
  const float* linzn_b  = (const float*)d_in[26];
  const float* act0_w   = (const float*)d_in[27];
  const float* act0_b   = (const float*)d_in[28];
  const float* act1_w   = (const float*)d_in[29];
  const float* act1_b   = (const float*)d_in[30];
  const float* linact_w = (const float*)d_in[31];
  const float* linact_b = (const float*)d_in[32];
  float* out = (float*)d_out;

  nmstpp_fused<<<dim3(BATCH / 2), dim3(NT), 0, stream>>>(
      X, emb_act, emb_zone, lin0_w, lin0_b, qkv_w, qkv_b, attn_o_w, attn_o_b,
      ln1_g, ln1_b, ff1_w, ff1_b, ff2_w, ff2_b, ln2_g, ln2_b,
      relu_w, relu_b, dT_w, dT_b, lindT_w, lindT_b, zn_w, zn_b,
      linzn_w, linzn_b, act0_w, act0_b, act1_w, act1_b, linact_w, linact_b,
      out);
}

// Round 8
// 278.498 us; speedup vs baseline: 1.0431x; 1.0431x over previous
//
#include <hip/hip_runtime.h>
#include <math.h>

#define BATCH 512
#define SEQ   256
#define DIM   256
#define NHEAD 8
#define DFF   1024
#define NT    1024
#define NWAVE 16

// ---------- helpers ----------

__device__ __forceinline__ float dot4f(float4 a, float4 b) {
  return fmaf(a.x, b.x, fmaf(a.y, b.y, fmaf(a.z, b.z, a.w * b.w)));
}

__device__ __forceinline__ float wave_allred(float v) {
  #pragma unroll
  for (int off = 32; off > 0; off >>= 1) v += __shfl_xor(v, off, 64);
  return v;
}

// 4-step reduce across the 16 kj-lanes
__device__ __forceinline__ float red16(float v) {
  v += __shfl_xor(v, 1, 16);
  v += __shfl_xor(v, 2, 16);
  v += __shfl_xor(v, 4, 16);
  v += __shfl_xor(v, 8, 16);
  return v;
}

// per-half (batch) block sum; ALL 1024 threads must call
__device__ __forceinline__ float half_sum(float v, float* red) {
  const int tid = threadIdx.x;
  v = wave_allred(v);
  __syncthreads();
  if ((tid & 63) == 0) red[tid >> 6] = v;
  __syncthreads();
  const int base = (tid >= 512) ? 8 : 0;
  float s = 0.f;
  #pragma unroll
  for (int i = 0; i < 8; ++i) s += red[base + i];
  return s;
}

struct XReg { float4 v[4]; };

__device__ __forceinline__ void load_xreg(const float* __restrict__ x, int kj, XReg& xr) {
  #pragma unroll
  for (int i = 0; i < 4; ++i) xr.v[i] = *(const float4*)(x + 4 * kj + 64 * i);
}

// one 256-row GEMV pass over this thread's K-slice; rows r = slot + 64m
__device__ __forceinline__ void gemv_pass(const float* __restrict__ W, int ldw, int koff,
                                          int slot, int kj,
                                          const XReg& x0, const XReg& x1,
                                          float acc[4][2]) {
  #pragma unroll
  for (int mp = 0; mp < 2; ++mp) {             // m-pairs: 8 loads in flight
    float4 w[2][4];
    #pragma unroll
    for (int mm = 0; mm < 2; ++mm) {
      const float* wr = W + (size_t)(slot + 64 * (2 * mp + mm)) * ldw + koff + 4 * kj;
      #pragma unroll
      for (int i = 0; i < 4; ++i) w[mm][i] = *(const float4*)(wr + 64 * i);
    }
    #pragma unroll
    for (int mm = 0; mm < 2; ++mm) {
      float a0 = 0.f, a1 = 0.f;
      #pragma unroll
      for (int i = 0; i < 4; ++i) {
        a0 += dot4f(w[mm][i], x0.v[i]);
        a1 += dot4f(w[mm][i], x1.v[i]);
      }
      acc[2 * mp + mm][0] += a0;
      acc[2 * mp + mm][1] += a1;
    }
  }
}

struct BatchBuf {
  float sc[2048];     // w~ [d][h] -> scores [h][s] -> att [s][h] -> u [h][d] -> ffb -> z1/a0/a1
  float pe[SEQ];
  float srcl[DIM];
  float qv[DIM];      // q -> tv(LN1) -> tv(LN2)
  float ao[DIM];
  float h1[DIM];      // h1 -> d1
  float h2[DIM];
  float xr[DIM];
  float znin[260];
  float fa[280];
  float znv[20];
  float cb[8];
  float scA[9 * 8];
  float scZ[20 * 8];
  float mHJ[8 * 8];
  float biasO8[8];
  float wsum8[8];
  float attA[8 * 9];
  float attZ[8 * 20];
  float oAcc[8 * 7];
  float peAcc8[8];
  int   Xa[SEQ];
  int   Xz[SEQ];
  float Xo[SEQ * 7];
};

// ---------- fused kernel: TWO batch elements per block ----------
// amdgpu_waves_per_eu(4,4): pin occupancy to exactly 4 waves/EU (16 waves/CU =
// 1 block/CU) so the register allocator gets the full 2048/4 = 128 VGPR budget.
// __launch_bounds__' 2nd arg is only a MINIMUM waves/EU — the compiler still
// targeted 8/EU (VGPR=64) and spilled ~1KB/thread (rounds 5/7: 232MB FETCH,
// 258MB WRITE of scratch traffic).

__global__ __launch_bounds__(NT)
__attribute__((amdgpu_waves_per_eu(4, 4)))
void nmstpp_fused(
    const int*   __restrict__ X,
    const float* __restrict__ emb_act,
    const float* __restrict__ emb_zone,
    const float* __restrict__ lin0_w,
    const float* __restrict__ lin0_b,
    const float* __restrict__ qkv_w,
    const float* __restrict__ qkv_b,
    const float* __restrict__ attn_o_w,
    const float* __restrict__ attn_o_b,
    const float* __restrict__ ln1_g, const float* __restrict__ ln1_b,
    const float* __restrict__ ff1_w,
    const float* __restrict__ ff1_b,
    const float* __restrict__ ff2_w,
    const float* __restrict__ ff2_b,
    const float* __restrict__ ln2_g, const float* __restrict__ ln2_b,
    const float* __restrict__ relu_w,
    const float* __restrict__ relu_b,
    const float* __restrict__ dT_w,
    const float* __restrict__ dT_b,
    const float* __restrict__ lindT_w,
    const float* __restrict__ lindT_b,
    const float* __restrict__ zn_w,
    const float* __restrict__ zn_b,
    const float* __restrict__ linzn_w,
    const float* __restrict__ linzn_b,
    const float* __restrict__ act0_w,
    const float* __restrict__ act0_b,
    const float* __restrict__ act1_w,
    const float* __restrict__ act1_b,
    const float* __restrict__ linact_w,
    const float* __restrict__ linact_b,
    float* __restrict__ out)
{
  const int tid   = threadIdx.x;
  const int wid   = tid >> 6;
  const int lane  = tid & 63;
  const int batch = tid >> 9;        // 0 or 1 (half-block)
  const int tp    = tid & 511;       // index within half
  const int b     = 2 * blockIdx.x + batch;
  const int kj    = tid & 15;        // K-split lane
  const int slot  = tid >> 4;        // row slot [0,64)

  __shared__ alignas(16) BatchBuf bb[2];
  __shared__ float embA[9 * 65];
  __shared__ float embZ[20 * 65];
  __shared__ float l0w[128 * 7];
  __shared__ float l0b[128];
  __shared__ float red[NWAVE];

  BatchBuf* mb = &bb[batch];
  float* sc0 = bb[0].sc;
  float* sc1 = bb[1].sc;

  // ---- phase 0: stage shared tables + per-batch X / pe ----
  for (int i = tid; i < 9 * 64;  i += NT) embA[(i >> 6) * 65 + (i & 63)] = emb_act[i];
  for (int i = tid; i < 20 * 64; i += NT) embZ[(i >> 6) * 65 + (i & 63)] = emb_zone[i];
  for (int i = tid; i < 128 * 7; i += NT) l0w[i] = lin0_w[i];
  if (tid < 128) l0b[tid] = lin0_b[tid];
  if (tp < SEQ) {
    const int* xrow = X + (b * SEQ + tp) * 9;
    mb->Xa[tp] = xrow[0];
    mb->Xz[tp] = xrow[1];
    #pragma unroll
    for (int j = 0; j < 7; ++j) mb->Xo[tp * 7 + j] = (float)xrow[2 + j];
    float ex  = (float)(2 * tp) / (float)SEQ;
    float ang = (float)b * exp2f(-ex * 6.643856189774724f);  // 100^-ex
    mb->pe[tp] = ((tp & 1) == 0) ? sinf(ang) : cosf(ang);
  }
  __syncthreads();

  // ---- phase 1: src at last position ----
  if (tp < DIM) {
    int av = mb->Xa[SEQ - 1], zv = mb->Xz[SEQ - 1];
    float v;
    if (tp < 64)        v = embA[av * 65 + tp];
    else if (tp < 128)  v = embZ[zv * 65 + (tp - 64)];
    else {
      const float* lr = l0w + (tp - 128) * 7;
      float acc = l0b[tp - 128];
      #pragma unroll
      for (int j = 0; j < 7; ++j) acc = fmaf(lr[j], mb->Xo[(SEQ - 1) * 7 + j], acc);
      v = acc;
    }
    mb->srcl[tp] = v + mb->pe[SEQ - 1];
  }
  __syncthreads();

  // ---- phase 2: q = Wq @ srcl + bq (16-lane K-split, 4 rows/thread) ----
  {
    XReg x0, x1;
    load_xreg(bb[0].srcl, kj, x0);
    load_xreg(bb[1].srcl, kj, x1);
    float acc[4][2] = {};
    gemv_pass(qkv_w, 256, 0, slot, kj, x0, x1, acc);
    #pragma unroll
    for (int m = 0; m < 4; ++m) {
      float s0 = red16(acc[m][0]);
      float s1 = red16(acc[m][1]);
      if (kj == 0) {
        int r = slot + 64 * m;
        float bv = qkv_b[r];
        bb[0].qv[r] = s0 + bv;
        bb[1].qv[r] = s1 + bv;
      }
    }
  }
  __syncthreads();

  // ---- phase 3: w~[d][h] (coalesced column sweep; each half does its batch) ----
  {
    const float inv = 0.17677669529663687f;  // 1/sqrt(32)
    const int d = tp & 255;
    const int hbase = (tp < 256) ? 0 : 4;
    float acc[4] = {0.f, 0.f, 0.f, 0.f};
    for (int c = 0; c < 32; ++c) {
      #pragma unroll
      for (int hh = 0; hh < 4; ++hh) {
        int h = hbase + hh;
        acc[hh] = fmaf(mb->qv[h * 32 + c], qkv_w[(DIM + h * 32 + c) * DIM + d], acc[hh]);
      }
    }
    #pragma unroll
    for (int hh = 0; hh < 4; ++hh) mb->sc[d * 8 + hbase + hh] = acc[hh] * inv;
  }
  __syncthreads();

  // ---- phase 3.5: collapse scores into lookup tables ----
  {
    if (tp < 296) {
      int h = tp / 37, k = tp - h * 37;
      if (k < 9) {
        float acc = 0.f;
        for (int c = 0; c < 64; ++c) acc = fmaf(mb->sc[c * 8 + h], embA[k * 65 + c], acc);
        mb->scA[k * 8 + h] = acc;
      } else if (k < 29) {
        int z = k - 9; float acc = 0.f;
        for (int c = 0; c < 64; ++c) acc = fmaf(mb->sc[(64 + c) * 8 + h], embZ[z * 65 + c], acc);
        mb->scZ[z * 8 + h] = acc;
      } else if (k < 36) {
        int j = k - 29; float acc = 0.f;
        for (int kk = 0; kk < 128; ++kk) acc = fmaf(mb->sc[(128 + kk) * 8 + h], l0w[kk * 7 + j], acc);
        mb->mHJ[h * 8 + j] = acc;
      } else {
        float acc = 0.f;
        for (int c = 0; c < 256; ++c) acc += mb->sc[c * 8 + h];
        mb->wsum8[h] = acc;
      }
    } else if (tp < 304) {
      int h = tp - 296; float acc = 0.f;
      for (int kk = 0; kk < 128; ++kk) acc = fmaf(mb->sc[(128 + kk) * 8 + h], l0b[kk], acc);
      mb->biasO8[h] = acc;
    } else if (tp < 312) {
      int h = tp - 304; float acc = 0.f;
      for (int c = 0; c < 32; ++c) acc += mb->qv[h * 32 + c] * qkv_b[DIM + h * 32 + c];
      mb->cb[h] = acc * 0.17677669529663687f;
    }
  }
  __syncthreads();

  // ---- phase 4: scores via tables (thread = position) ----
  if (tp < SEQ) {
    const int s = tp;
    int av = mb->Xa[s], zv = mb->Xz[s];
    float o[7];
    #pragma unroll
    for (int j = 0; j < 7; ++j) o[j] = mb->Xo[s * 7 + j];
    float pes = mb->pe[s];
    #pragma unroll
    for (int h = 0; h < NHEAD; ++h) {
      float acc = mb->scA[av * 8 + h] + mb->scZ[zv * 8 + h] + mb->biasO8[h] + mb->cb[h];
      acc = fmaf(pes, mb->wsum8[h], acc);
      #pragma unroll
      for (int j = 0; j < 7; ++j) acc = fmaf(mb->mHJ[h * 8 + j], o[j], acc);
      mb->sc[h * SEQ + s] = acc;
    }
  }
  __syncthreads();

  // ---- phase 5: softmax per head, in-place transpose (reg-staged) ----
  {
    float vals[8]; float rinv = 0.f;
    int h = tp >> 5, idx = tp & 31;
    if (tp < 256) {
      float m = -1e30f;
      #pragma unroll
      for (int i = 0; i < 8; ++i) {
        vals[i] = mb->sc[h * SEQ + idx * 8 + i];
        m = fmaxf(m, vals[i]);
      }
      #pragma unroll
      for (int off = 16; off > 0; off >>= 1) m = fmaxf(m, __shfl_xor(m, off, 32));
      float lsum = 0.f;
      #pragma unroll
      for (int i = 0; i < 8; ++i) { vals[i] = expf(vals[i] - m); lsum += vals[i]; }
      #pragma unroll
      for (int off = 16; off > 0; off >>= 1) lsum += __shfl_xor(lsum, off, 32);
      rinv = 1.0f / lsum;
    }
    __syncthreads();
    if (tp < 256) {
      #pragma unroll
      for (int i = 0; i < 8; ++i) mb->sc[(idx * 8 + i) * 8 + h] = vals[i] * rinv;
    }
  }
  __syncthreads();

  // ---- phase 6a: attention-weighted histograms / moments ----
  if (tp < 296) {
    int h = tp / 37, k = tp - h * 37;
    float acc = 0.f;
    if (k < 29) {
      int mybin = (k < 9) ? k : (k - 9);
      const int* bins = (k < 9) ? mb->Xa : mb->Xz;
      for (int s = 0; s < SEQ; ++s) {
        float at = mb->sc[s * 8 + h];
        acc += (bins[s] == mybin) ? at : 0.f;
      }
      if (k < 9) mb->attA[h * 9 + k] = acc; else mb->attZ[h * 20 + (k - 9)] = acc;
    } else if (k < 36) {
      int j = k - 29;
      for (int s = 0; s < SEQ; ++s) acc = fmaf(mb->sc[s * 8 + h], mb->Xo[s * 7 + j], acc);
      mb->oAcc[h * 7 + j] = acc;
    } else {
      for (int s = 0; s < SEQ; ++s) acc = fmaf(mb->sc[s * 8 + h], mb->pe[s], acc);
      mb->peAcc8[h] = acc;
    }
  }
  __syncthreads();

  // ---- phase 6b: reconstruct u[h][d] (overwrites att) ----
  if (tp < DIM) {
    float acc[NHEAD];
    #pragma unroll
    for (int h = 0; h < NHEAD; ++h) acc[h] = mb->peAcc8[h];
    if (tp < 64) {
      for (int a = 0; a < 9; ++a) {
        float ev = embA[a * 65 + tp];
        #pragma unroll
        for (int h = 0; h < NHEAD; ++h) acc[h] = fmaf(mb->attA[h * 9 + a], ev, acc[h]);
      }
    } else if (tp < 128) {
      int d = tp - 64;
      for (int z = 0; z < 20; ++z) {
        float ev = embZ[z * 65 + d];
        #pragma unroll
        for (int h = 0; h < NHEAD; ++h) acc[h] = fmaf(mb->attZ[h * 20 + z], ev, acc[h]);
      }
    } else {
      int kk = tp - 128;
      #pragma unroll
      for (int j = 0; j < 7; ++j) {
        float ov = l0w[kk * 7 + j];
        #pragma unroll
        for (int h = 0; h < NHEAD; ++h) acc[h] = fmaf(mb->oAcc[h * 7 + j], ov, acc[h]);
      }
      #pragma unroll
      for (int h = 0; h < NHEAD; ++h) acc[h] += l0b[kk];
    }
    #pragma unroll
    for (int h = 0; h < NHEAD; ++h) mb->sc[h * DIM + tp] = acc[h];
  }
  __syncthreads();

  // ---- phase 7: ao = Wv @ u + bv (head-grouped rows so x is per-thread fixed) ----
  {
    const int h = slot >> 3;
    const int rbase = h * 32 + (slot & 7);
    XReg x0, x1;
    load_xreg(sc0 + h * DIM, kj, x0);
    load_xreg(sc1 + h * DIM, kj, x1);
    #pragma unroll
    for (int mp = 0; mp < 2; ++mp) {
      float4 w[2][4];
      #pragma unroll
      for (int mm = 0; mm < 2; ++mm) {
        int r = rbase + 8 * (2 * mp + mm);
        const float* wr = qkv_w + (size_t)(2 * DIM + r) * DIM + 4 * kj;
        #pragma unroll
        for (int i = 0; i < 4; ++i) w[mm][i] = *(const float4*)(wr + 64 * i);
      }
      #pragma unroll
      for (int mm = 0; mm < 2; ++mm) {
        float a0 = 0.f, a1 = 0.f;
        #pragma unroll
        for (int i = 0; i < 4; ++i) {
          a0 += dot4f(w[mm][i], x0.v[i]);
          a1 += dot4f(w[mm][i], x1.v[i]);
        }
        a0 = red16(a0); a1 = red16(a1);
        if (kj == 0) {
          int r = rbase + 8 * (2 * mp + mm);
          float bv = qkv_b[2 * DIM + r];
          bb[0].ao[r] = bv + a0;
          bb[1].ao[r] = bv + a1;
        }
      }
    }
  }
  __syncthreads();

  // ---- phase 8: tv = srcl + attn_o(ao); h1 = LN1(tv) ----
  {
    XReg x0, x1;
    load_xreg(bb[0].ao, kj, x0);
    load_xreg(bb[1].ao, kj, x1);
    float acc[4][2] = {};
    gemv_pass(attn_o_w, 256, 0, slot, kj, x0, x1, acc);
    #pragma unroll
    for (int m = 0; m < 4; ++m) {
      float s0 = red16(acc[m][0]);
      float s1 = red16(acc[m][1]);
      if (kj == 0) {
        int r = slot + 64 * m;
        float bv = attn_o_b[r];
        bb[0].qv[r] = bb[0].srcl[r] + bv + s0;
        bb[1].qv[r] = bb[1].srcl[r] + bv + s1;
      }
    }
  }
  __syncthreads();
  {
    float tv = (tp < DIM) ? mb->qv[tp] : 0.f;
    float mean = half_sum(tv, red) * (1.0f / 256.0f);
    float dv = (tp < DIM) ? (tv - mean) : 0.f;
    float var = half_sum(dv * dv, red) * (1.0f / 256.0f);
    if (tp < DIM) mb->h1[tp] = dv / sqrtf(var + 1e-5f) * ln1_g[tp] + ln1_b[tp];
  }
  __syncthreads();

  // ---- phase 9: ffb = relu(ff1 @ h1 + b) (4 row-passes) ----
  {
    XReg x0, x1;
    load_xreg(bb[0].h1, kj, x0);
    load_xreg(bb[1].h1, kj, x1);
    #pragma unroll
    for (int p = 0; p < 4; ++p) {
      float acc[4][2] = {};
      gemv_pass(ff1_w + (size_t)(256 * p) * 256, 256, 0, slot, kj, x0, x1, acc);
      #pragma unroll
      for (int m = 0; m < 4; ++m) {
        float s0 = red16(acc[m][0]);
        float s1 = red16(acc[m][1]);
        if (kj == 0) {
          int r = 256 * p + slot + 64 * m;
          float bv = ff1_b[r];
          sc0[r] = fmaxf(s0 + bv, 0.f);
          sc1[r] = fmaxf(s1 + bv, 0.f);
        }
      }
    }
  }
  __syncthreads();

  // ---- phase 10: tv = h1 + ff2 @ ffb + b; h2 = LN2(tv) (4 K-passes) ----
  {
    float acc[4][2] = {};
    #pragma unroll
    for (int p = 0; p < 4; ++p) {
      XReg x0, x1;
      load_xreg(sc0 + 256 * p, kj, x0);
      load_xreg(sc1 + 256 * p, kj, x1);
      gemv_pass(ff2_w, 1024, 256 * p, slot, kj, x0, x1, acc);
    }
    #pragma unroll
    for (int m = 0; m < 4; ++m) {
      float s0 = red16(acc[m][0]);
      float s1 = red16(acc[m][1]);
      if (kj == 0) {
        int r = slot + 64 * m;
        float bv = ff2_b[r];
        bb[0].qv[r] = bb[0].h1[r] + bv + s0;
        bb[1].qv[r] = bb[1].h1[r] + bv + s1;
      }
    }
  }
  __syncthreads();
  {
    float tv = (tp < DIM) ? mb->qv[tp] : 0.f;
    float mean = half_sum(tv, red) * (1.0f / 256.0f);
    float dv = (tp < DIM) ? (tv - mean) : 0.f;
    float var = half_sum(dv * dv, red) * (1.0f / 256.0f);
    if (tp < DIM) mb->h2[tp] = dv / sqrtf(var + 1e-5f) * ln2_g[tp] + ln2_b[tp];
  }
  __syncthreads();

  // ---- phase 11: xr = relu_w @ h2 + b ----
  {
    XReg x0, x1;
    load_xreg(bb[0].h2, kj, x0);
    load_xreg(bb[1].h2, kj, x1);
    float acc[4][2] = {};
    gemv_pass(relu_w, 256, 0, slot, kj, x0, x1, acc);
    #pragma unroll
    for (int m = 0; m < 4; ++m) {
      float s0 = red16(acc[m][0]);
      float s1 = red16(acc[m][1]);
      if (kj == 0) {
        int r = slot + 64 * m;
        float bv = relu_b[r];
        bb[0].xr[r] = bv + s0;
        bb[1].xr[r] = bv + s1;
      }
    }
  }
  __syncthreads();

  // ---- phase 12: d1 = dT_w @ xr + b; dT = lindT . d1 + b ----
  {
    XReg x0, x1;
    load_xreg(bb[0].xr, kj, x0);
    load_xreg(bb[1].xr, kj, x1);
    float acc[4][2] = {};
    gemv_pass(dT_w, 256, 0, slot, kj, x0, x1, acc);
    #pragma unroll
    for (int m = 0; m < 4; ++m) {
      float s0 = red16(acc[m][0]);
      float s1 = red16(acc[m][1]);
      if (kj == 0) {
        int r = slot + 64 * m;
        float bv = dT_b[r];
        bb[0].h1[r] = bv + s0;               // h1 = d1
        bb[1].h1[r] = bv + s1;
      }
    }
  }
  __syncthreads();
  float dTv;
  {
    float v = (tp < DIM) ? lindT_w[tp] * mb->h1[tp] : 0.f;
    dTv = half_sum(v, red) + lindT_b[0];
  }

  // ---- phase 13: zn path (row pairs, wave-per-pair) ----
  if (tp < DIM) { mb->znin[1 + tp] = mb->xr[tp]; mb->fa[21 + tp] = mb->xr[tp]; }
  if (tp == 0)  { mb->znin[0] = dTv; mb->fa[20] = dTv; }
  __syncthreads();
  float* z1_0 = sc0 + 1024; float* z1_1 = sc1 + 1024;
  for (int r0 = 2 * wid; r0 < 257; r0 += 32) {
    int r1 = r0 + 1;
    bool has2 = (r1 < 257);
    const float* wa = zn_w + (size_t)r0 * 257;
    const float* wb = zn_w + (size_t)r1 * 257;
    float pa0 = 0.f, pa1 = 0.f, pb0 = 0.f, pb1 = 0.f;
    for (int j = lane; j < 257; j += 64) {
      float xa = bb[0].znin[j], xb = bb[1].znin[j];
      float w0 = wa[j];
      pa0 = fmaf(w0, xa, pa0); pa1 = fmaf(w0, xb, pa1);
      if (has2) { float w1 = wb[j]; pb0 = fmaf(w1, xa, pb0); pb1 = fmaf(w1, xb, pb1); }
    }
    pa0 = wave_allred(pa0); pa1 = wave_allred(pa1);
    pb0 = wave_allred(pb0); pb1 = wave_allred(pb1);
    if (lane == 0) {
      z1_0[r0] = zn_b[r0] + pa0; z1_1[r0] = zn_b[r0] + pa1;
      if (has2) { z1_0[r1] = zn_b[r1] + pb0; z1_1[r1] = zn_b[r1] + pb1; }
    }
  }
  __syncthreads();
  for (int r0 = 2 * wid; r0 < 20; r0 += 32) {
    int r1 = r0 + 1;
    const float* wa = linzn_w + (size_t)r0 * 257;
    const float* wb = linzn_w + (size_t)r1 * 257;
    float pa0 = 0.f, pa1 = 0.f, pb0 = 0.f, pb1 = 0.f;
    for (int j = lane; j < 257; j += 64) {
      float x0v = z1_0[j], x1v = z1_1[j];
      float w0 = wa[j], w1 = wb[j];
      pa0 = fmaf(w0, x0v, pa0); pa1 = fmaf(w0, x1v, pa1);
      pb0 = fmaf(w1, x0v, pb0); pb1 = fmaf(w1, x1v, pb1);
    }
    pa0 = wave_allred(pa0); pa1 = wave_allred(pa1);
    pb0 = wave_allred(pb0); pb1 = wave_allred(pb1);
    if (lane == 0) {
      bb[0].znv[r0] = linzn_b[r0] + pa0; bb[0].fa[r0] = linzn_b[r0] + pa0;
      bb[1].znv[r0] = linzn_b[r0] + pa1; bb[1].fa[r0] = linzn_b[r0] + pa1;
      bb[0].znv[r1] = linzn_b[r1] + pb0; bb[0].fa[r1] = linzn_b[r1] + pb0;
      bb[1].znv[r1] = linzn_b[r1] + pb1; bb[1].fa[r1] = linzn_b[r1] + pb1;
    }
  }
  __syncthreads();

  // ---- phase 14: ac = linact @ act1 @ act0 @ fa (row pairs) ----
  float* a0_0 = sc0 + 1312; float* a0_1 = sc1 + 1312;
  for (int r0 = 2 * wid; r0 < 277; r0 += 32) {
    int r1 = r0 + 1;
    bool has2 = (r1 < 277);
    const float* wa = act0_w + (size_t)r0 * 277;
    const float* wb = act0_w + (size_t)r1 * 277;
    float pa0 = 0.f, pa1 = 0.f, pb0 = 0.f, pb1 = 0.f;
    for (int j = lane; j < 277; j += 64) {
      float xa = bb[0].fa[j], xb = bb[1].fa[j];
      float w0 = wa[j];
      pa0 = fmaf(w0, xa, pa0); pa1 = fmaf(w0, xb, pa1);
      if (has2) { float w1 = wb[j]; pb0 = fmaf(w1, xa, pb0); pb1 = fmaf(w1, xb, pb1); }
    }
    pa0 = wave_allred(pa0); pa1 = wave_allred(pa1);
    pb0 = wave_allred(pb0); pb1 = wave_allred(pb1);
    if (lane == 0) {
      a0_0[r0] = act0_b[r0] + pa0; a0_1[r0] = act0_b[r0] + pa1;
      if (has2) { a0_0[r1] = act0_b[r1] + pb0; a0_1[r1] = act0_b[r1] + pb1; }
    }
  }
  __syncthreads();
  float* a1_0 = sc0 + 1024; float* a1_1 = sc1 + 1024;  // z1 dead
  for (int r0 = 2 * wid; r0 < 277; r0 += 32) {
    int r1 = r0 + 1;
    bool has2 = (r1 < 277);
    const float* wa = act1_w + (size_t)r0 * 277;
    const float* wb = act1_w + (size_t)r1 * 277;
    float pa0 = 0.f, pa1 = 0.f, pb0 = 0.f, pb1 = 0.f;
    for (int j = lane; j < 277; j += 64) {
      float xa = a0_0[j], xb = a0_1[j];
      float w0 = wa[j];
      pa0 = fmaf(w0, xa, pa0); pa1 = fmaf(w0, xb, pa1);
      if (has2) { float w1 = wb[j]; pb0 = fmaf(w1, xa, pb0); pb1 = fmaf(w1, xb, pb1); }
    }
    pa0 = wave_allred(pa0); pa1 = wave_allred(pa1);
    pb0 = wave_allred(pb0); pb1 = wave_allred(pb1);
    if (lane == 0) {
      a1_0[r0] = act1_b[r0] + pa0; a1_1[r0] = act1_b[r0] + pa1;
      if (has2) { a1_0[r1] = act1_b[r1] + pb0; a1_1[r1] = act1_b[r1] + pb1; }
    }
  }
  __syncthreads();

  // ---- phase 15: outputs ----
  for (int r = wid; r < 5; r += 16) {
    const float* wr = linact_w + (size_t)r * 277;
    float p0 = 0.f, p1 = 0.f;
    for (int j = lane; j < 277; j += 64) {
      float w = wr[j];
      p0 = fmaf(w, a1_0[j], p0);
      p1 = fmaf(w, a1_1[j], p1);
    }
    p0 = wave_allred(p0); p1 = wave_allred(p1);
    if (lane == 0) {
      out[(2 * blockIdx.x)     * 26 + 21 + r] = linact_b[r] + p0;
      out[(2 * blockIdx.x + 1) * 26 + 21 + r] = linact_b[r] + p1;
    }
  }
  if (tp == 0) out[b * 26] = dTv;
  if (tp < 20) out[b * 26 + 1 + tp] = mb->znv[tp];
}

// ---------- launcher ----------

extern "C" void kernel_launch(void* const* d_in, const int* in_sizes, int n_in,
                              void* d_out, int out_size, void* d_ws, size_t ws_size,
                              hipStream_t stream) {
  (void)in_sizes; (void)n_in; (void)d_ws; (void)ws_size; (void)out_size;
  const int*   X        = (const int*)  d_in[0];
  const float* emb_act  = (const float*)d_in[1];
  const float* emb_zone = (const float*)d_in[2];
  const float* lin0_w   = (const float*)d_in[3];
  const float* lin0_b   = (const float*)d_in[4];
  const float* qkv_w    = (const float*)d_in[5];
  const float* qkv_b    = (const float*)d_in[6];
  const float* attn_o_w = (const float*)d_in[7];
  const float* attn_o_b = (const float*)d_in[8];
  const float* ln1_g    = (const float*)d_in[9];
  const float* ln1_b    = (const float*)d_in[10];
  const float* ff1_w    = (const float*)d_in[11];
  const float* ff1_b    = (const float*)d_in[12];
  const float* ff2_w    = (const float*)d_in[13];
  const float* ff2_b    = (const float*)d_in[14];
  const float* ln2_g    = (const float*)d_in[15];
  const float* ln2_b    = (const float*)d_in[16];
  const float* relu_w   = (const float*)d_in[17];
  const float* relu_b   = (const float*)d_in[18];
  const float* dT_w     = (const float*)d_in[19];
  const float* dT_b     = (const float*)d_in[20];
  const float* lindT_w  = (const float*)d_in[21];
  const float* lindT_b  = (const float*)d_in[22];
  const float* zn_w     = (const float*)d_in[23];
  const float* zn_b     = (const float*)d_in[24];
  const float* linzn_w  = (const float*)d_in[25];
  const float* linzn_b  = (const float*)d_in[26];
  const float* act0_w   = (const float*)d_in[27];
  const float* act0_b   = (const float*)d_in[28];
  const float* act1_w   = (const float*)d_in[29];
  const float* act1_b   = (const float*)d_in[30];
  const float* linact_w = (const float*)d_in[31];
  const float* linact_b = (const float*)d_in[32];
  float* out = (float*)d_out;

  nmstpp_fused<<<dim3(BATCH / 2), dim3(NT), 0, stream>>>(
      X, emb_act, emb_zone, lin0_w, lin0_b, qkv_w, qkv_b, attn_o_w, attn_o_b,
      ln1_g, ln1_b, ff1_w, ff1_b, ff2_w, ff2_b, ln2_g, ln2_b,
      relu_w, relu_b, dT_w, dT_b, lindT_w, lindT_b, zn_w, zn_b,
      linzn_w, linzn_b, act0_w, act0_b, act1_w, act1_b, linact_w, linact_b,
      out);
}

// Round 9
// 218.514 us; speedup vs baseline: 1.3294x; 1.2745x over previous
//
#include <hip/hip_runtime.h>
#include <math.h>

#define BATCH 512
#define SEQ   256
#define DIM   256
#define NHEAD 8
#define DFF   1024
#define NT    512   // threads per block
#define NW    8     // waves per block

// ---------- helpers ----------

__device__ __forceinline__ float dot4f(float4 a, float4 b) {
  return fmaf(a.x, b.x, fmaf(a.y, b.y, fmaf(a.z, b.z, a.w * b.w)));
}

__device__ __forceinline__ float wave_allred(float v) {
  #pragma unroll
  for (int off = 32; off > 0; off >>= 1) v += __shfl_xor(v, off, 64);
  return v;
}

// Reduce 8 values across 64 lanes simultaneously (4 rows x 2 batches).
// Result groups of 8 lanes: g=lane>>3:
//   g0:r0b0 g1:r2b0 g2:r1b0 g3:r3b0 g4:r0b1 g5:r2b1 g6:r1b1 g7:r3b1
// row offset for g: ((g&1)<<4) | ((g&2)<<2); batch = g>>2.
__device__ __forceinline__ float fold8(int lane,
    float r0b0, float r0b1, float r1b0, float r1b1,
    float r2b0, float r2b1, float r3b0, float r3b1) {
  float z0 = (lane & 32) ? r0b1 : r0b0;
  float t0 = (lane & 32) ? r0b0 : r0b1;
  z0 += __shfl_xor(t0, 32, 64);
  float z1 = (lane & 32) ? r1b1 : r1b0;
  float t1 = (lane & 32) ? r1b0 : r1b1;
  z1 += __shfl_xor(t1, 32, 64);
  float z2 = (lane & 32) ? r2b1 : r2b0;
  float t2 = (lane & 32) ? r2b0 : r2b1;
  z2 += __shfl_xor(t2, 32, 64);
  float z3 = (lane & 32) ? r3b1 : r3b0;
  float t3 = (lane & 32) ? r3b0 : r3b1;
  z3 += __shfl_xor(t3, 32, 64);
  float w01 = (lane & 16) ? z1 : z0;
  float s01 = (lane & 16) ? z0 : z1;
  w01 += __shfl_xor(s01, 16, 64);
  float w23 = (lane & 16) ? z3 : z2;
  float s23 = (lane & 16) ? z2 : z3;
  w23 += __shfl_xor(s23, 16, 64);
  float u = (lane & 8) ? w23 : w01;
  float t = (lane & 8) ? w01 : w23;
  u += __shfl_xor(t, 8, 64);
  u += __shfl_xor(u, 4, 64);
  u += __shfl_xor(u, 2, 64);
  u += __shfl_xor(u, 1, 64);
  return u;
}

// Reduce 4 values (2 rows x 2 batches). Groups of 16 lanes:
//   g=lane>>4: g0: rowA b0, g1: rowB b0, g2: rowA b1, g3: rowB b1
__device__ __forceinline__ float fold4(int lane, float a0, float a1, float b0, float b1) {
  float za = (lane & 32) ? a1 : a0;
  float ta = (lane & 32) ? a0 : a1;
  za += __shfl_xor(ta, 32, 64);
  float zb = (lane & 32) ? b1 : b0;
  float tb = (lane & 32) ? b0 : b1;
  zb += __shfl_xor(tb, 32, 64);
  float u = (lane & 16) ? zb : za;
  float t = (lane & 16) ? za : zb;
  u += __shfl_xor(t, 16, 64);
  u += __shfl_xor(u, 8, 64);
  u += __shfl_xor(u, 4, 64);
  u += __shfl_xor(u, 2, 64);
  u += __shfl_xor(u, 1, 64);
  return u;
}

// per-batch sum (waves 0-3 = batch0, waves 4-7 = batch1); ALL 512 threads call
__device__ __forceinline__ float batch_sum(float v, float* red, int wid, int batch) {
  v = wave_allred(v);
  __syncthreads();
  if ((threadIdx.x & 63) == 0) red[wid] = v;
  __syncthreads();
  const int base = batch * 4;
  return red[base] + red[base + 1] + red[base + 2] + red[base + 3];
}

// 4-row dot (rows r, r+8, r+16, r+24) over K=LDW, both batches, folded.
template <int LDW>
__device__ __forceinline__ float rows4_dot(const float* __restrict__ W, int r, int lane,
                                           float4 x0, float4 x1) {
  const float* wp = W + (size_t)r * LDW + lane * 4;
  float4 w0 = *(const float4*)(wp);
  float4 w1 = *(const float4*)(wp + 8 * LDW);
  float4 w2 = *(const float4*)(wp + 16 * LDW);
  float4 w3 = *(const float4*)(wp + 24 * LDW);
  return fold8(lane,
               dot4f(w0, x0), dot4f(w0, x1),
               dot4f(w1, x0), dot4f(w1, x1),
               dot4f(w2, x0), dot4f(w2, x1),
               dot4f(w3, x0), dot4f(w3, x1));
}

__device__ __forceinline__ bool out_slot(int lane, int r, int& rr, int& bsel) {
  if ((lane & 7) != 0) return false;
  int g = lane >> 3;
  rr = r + (((g & 1) << 4) | ((g & 2) << 2));
  bsel = g >> 2;
  return true;
}

struct BatchBuf {
  float sc[2048];     // w~ [d][h] -> scores [h][s] -> att [s][h] -> u [h][d] -> ffb -> z1/a0/a1
  float pe[SEQ];
  float srcl[DIM];
  float qv[DIM];      // q -> tv(LN1) -> tv(LN2)
  float ao[DIM];
  float h1[DIM];      // h1 -> d1
  float h2[DIM];
  float xr[DIM];
  float znin[260];
  float fa[280];
  float znv[20];
  float cb[8];
  float scA[9 * 8];
  float scZ[20 * 8];
  float mHJ[8 * 8];
  float biasO8[8];
  float wsum8[8];
  float attA[8 * 9];
  float attZ[8 * 20];
  float oAcc[8 * 7];
  float peAcc8[8];
  int   Xa[SEQ];
  int   Xz[SEQ];
  float Xo[SEQ * 7];
};

// ---------- fused kernel: TWO batch elements per 512-thread block ----------
// 2 blocks/CU (LDS 70.6KB*2 <= 160KB, VGPR <= 128): independent blocks overlap
// each other's barrier stalls. GEMV phases: 4 rows x 2 batches per wave-iter,
// single fold8 butterfly (8 shuffles) reduces all 8 outputs at once.

__global__ __launch_bounds__(NT, 4) void nmstpp_fused(
    const int*   __restrict__ X,
    const float* __restrict__ emb_act,
    const float* __restrict__ emb_zone,
    const float* __restrict__ lin0_w,
    const float* __restrict__ lin0_b,
    const float* __restrict__ qkv_w,
    const float* __restrict__ qkv_b,
    const float* __restrict__ attn_o_w,
    const float* __restrict__ attn_o_b,
    const float* __restrict__ ln1_g, const float* __restrict__ ln1_b,
    const float* __restrict__ ff1_w,
    const float* __restrict__ ff1_b,
    const float* __restrict__ ff2_w,
    const float* __restrict__ ff2_b,
    const float* __restrict__ ln2_g, const float* __restrict__ ln2_b,
    const float* __restrict__ relu_w,
    const float* __restrict__ relu_b,
    const float* __restrict__ dT_w,
    const float* __restrict__ dT_b,
    const float* __restrict__ lindT_w,
    const float* __restrict__ lindT_b,
    const float* __restrict__ zn_w,
    const float* __restrict__ zn_b,
    const float* __restrict__ linzn_w,
    const float* __restrict__ linzn_b,
    const float* __restrict__ act0_w,
    const float* __restrict__ act0_b,
    const float* __restrict__ act1_w,
    const float* __restrict__ act1_b,
    const float* __restrict__ linact_w,
    const float* __restrict__ linact_b,
    float* __restrict__ out)
{
  const int tid   = threadIdx.x;
  const int wid   = tid >> 6;        // 0..7
  const int lane  = tid & 63;
  const int batch = tid >> 8;        // 0/1 for 256-split phases
  const int tp    = tid & 255;
  const int b     = 2 * blockIdx.x + batch;

  __shared__ alignas(16) BatchBuf bb[2];
  __shared__ float embA[9 * 65];
  __shared__ float embZ[20 * 65];
  __shared__ float l0w[128 * 7];
  __shared__ float l0b[128];
  __shared__ float red[NW];

  BatchBuf* mb = &bb[batch];
  float* sc0 = bb[0].sc;
  float* sc1 = bb[1].sc;

  // ---- phase 0: stage shared tables + per-batch X / pe ----
  for (int i = tid; i < 9 * 64;  i += NT) embA[(i >> 6) * 65 + (i & 63)] = emb_act[i];
  for (int i = tid; i < 20 * 64; i += NT) embZ[(i >> 6) * 65 + (i & 63)] = emb_zone[i];
  for (int i = tid; i < 128 * 7; i += NT) l0w[i] = lin0_w[i];
  if (tid < 128) l0b[tid] = lin0_b[tid];
  {
    const int* xrow = X + (b * SEQ + tp) * 9;
    mb->Xa[tp] = xrow[0];
    mb->Xz[tp] = xrow[1];
    #pragma unroll
    for (int j = 0; j < 7; ++j) mb->Xo[tp * 7 + j] = (float)xrow[2 + j];
    float ex  = (float)(2 * tp) / (float)SEQ;
    float ang = (float)b * exp2f(-ex * 6.643856189774724f);  // 100^-ex
    mb->pe[tp] = ((tp & 1) == 0) ? sinf(ang) : cosf(ang);
  }
  __syncthreads();

  // ---- phase 1: src at last position (channel tp, batch) ----
  {
    int av = mb->Xa[SEQ - 1], zv = mb->Xz[SEQ - 1];
    float v;
    if (tp < 64)        v = embA[av * 65 + tp];
    else if (tp < 128)  v = embZ[zv * 65 + (tp - 64)];
    else {
      const float* lr = l0w + (tp - 128) * 7;
      float acc = l0b[tp - 128];
      #pragma unroll
      for (int j = 0; j < 7; ++j) acc = fmaf(lr[j], mb->Xo[(SEQ - 1) * 7 + j], acc);
      v = acc;
    }
    mb->srcl[tp] = v + mb->pe[SEQ - 1];
  }
  __syncthreads();

  // ---- phase 2: q = Wq @ srcl + bq ----
  {
    float4 x0 = *(const float4*)(bb[0].srcl + lane * 4);
    float4 x1 = *(const float4*)(bb[1].srcl + lane * 4);
    for (int k = 0; k < 8; ++k) {
      int r = wid + 32 * k;
      float u = rows4_dot<256>(qkv_w, r, lane, x0, x1);
      int rr, bsel;
      if (out_slot(lane, r, rr, bsel))
        (bsel ? bb[1].qv : bb[0].qv)[rr] = qkv_b[rr] + u;
    }
  }
  __syncthreads();

  // ---- phase 3: w~[d][h] (each weight load feeds both batches) ----
  {
    const float inv = 0.17677669529663687f;  // 1/sqrt(32)
    const int d = tid & 255;
    const int hbase = (tid < 256) ? 0 : 4;
    float acc[4][2] = {};
    for (int c = 0; c < 32; ++c) {
      #pragma unroll
      for (int hh = 0; hh < 4; ++hh) {
        int h = hbase + hh;
        float wv = qkv_w[(size_t)(DIM + h * 32 + c) * DIM + d];
        acc[hh][0] = fmaf(bb[0].qv[h * 32 + c], wv, acc[hh][0]);
        acc[hh][1] = fmaf(bb[1].qv[h * 32 + c], wv, acc[hh][1]);
      }
    }
    #pragma unroll
    for (int hh = 0; hh < 4; ++hh) {
      bb[0].sc[d * 8 + hbase + hh] = acc[hh][0] * inv;
      bb[1].sc[d * 8 + hbase + hh] = acc[hh][1] * inv;
    }
  }
  __syncthreads();

  // ---- phase 3.5: collapse scores into lookup tables (312 slots x 2 batches) ----
  for (int s5 = tid; s5 < 624; s5 += NT) {
    int bt = (s5 >= 312);
    int t2 = s5 - 312 * bt;
    BatchBuf* mx = &bb[bt];
    if (t2 < 296) {
      int h = t2 / 37, k = t2 - h * 37;
      if (k < 9) {
        float acc = 0.f;
        for (int c = 0; c < 64; ++c) acc = fmaf(mx->sc[c * 8 + h], embA[k * 65 + c], acc);
        mx->scA[k * 8 + h] = acc;
      } else if (k < 29) {
        int z = k - 9; float acc = 0.f;
        for (int c = 0; c < 64; ++c) acc = fmaf(mx->sc[(64 + c) * 8 + h], embZ[z * 65 + c], acc);
        mx->scZ[z * 8 + h] = acc;
      } else if (k < 36) {
        int j = k - 29; float acc = 0.f;
        for (int kk = 0; kk < 128; ++kk) acc = fmaf(mx->sc[(128 + kk) * 8 + h], l0w[kk * 7 + j], acc);
        mx->mHJ[h * 8 + j] = acc;
      } else {
        float acc = 0.f;
        for (int c = 0; c < 256; ++c) acc += mx->sc[c * 8 + h];
        mx->wsum8[h] = acc;
      }
    } else if (t2 < 304) {
      int h = t2 - 296; float acc = 0.f;
      for (int kk = 0; kk < 128; ++kk) acc = fmaf(mx->sc[(128 + kk) * 8 + h], l0b[kk], acc);
      mx->biasO8[h] = acc;
    } else {
      int h = t2 - 304; float acc = 0.f;
      for (int c = 0; c < 32; ++c) acc += mx->qv[h * 32 + c] * qkv_b[DIM + h * 32 + c];
      mx->cb[h] = acc * 0.17677669529663687f;
    }
  }
  __syncthreads();

  // ---- phase 4: scores via tables (thread = (position, batch)) ----
  {
    const int s = tp;
    int av = mb->Xa[s], zv = mb->Xz[s];
    float o[7];
    #pragma unroll
    for (int j = 0; j < 7; ++j) o[j] = mb->Xo[s * 7 + j];
    float pes = mb->pe[s];
    #pragma unroll
    for (int h = 0; h < NHEAD; ++h) {
      float acc = mb->scA[av * 8 + h] + mb->scZ[zv * 8 + h] + mb->biasO8[h] + mb->cb[h];
      acc = fmaf(pes, mb->wsum8[h], acc);
      #pragma unroll
      for (int j = 0; j < 7; ++j) acc = fmaf(mb->mHJ[h * 8 + j], o[j], acc);
      mb->sc[h * SEQ + s] = acc;
    }
  }
  __syncthreads();

  // ---- phase 5: softmax per head, in-place transpose ----
  {
    float vals[8];
    int h = tp >> 5, idx = tp & 31;
    float m = -1e30f;
    #pragma unroll
    for (int i = 0; i < 8; ++i) {
      vals[i] = mb->sc[h * SEQ + idx * 8 + i];
      m = fmaxf(m, vals[i]);
    }
    #pragma unroll
    for (int off = 16; off > 0; off >>= 1) m = fmaxf(m, __shfl_xor(m, off, 32));
    float lsum = 0.f;
    #pragma unroll
    for (int i = 0; i < 8; ++i) { vals[i] = expf(vals[i] - m); lsum += vals[i]; }
    #pragma unroll
    for (int off = 16; off > 0; off >>= 1) lsum += __shfl_xor(lsum, off, 32);
    float rinv = 1.0f / lsum;
    __syncthreads();
    #pragma unroll
    for (int i = 0; i < 8; ++i) mb->sc[(idx * 8 + i) * 8 + h] = vals[i] * rinv;
  }
  __syncthreads();

  // ---- phase 6a: attention-weighted histograms / moments (296 x 2) ----
  for (int s6 = tid; s6 < 592; s6 += NT) {
    int bt = (s6 >= 296);
    int t2 = s6 - 296 * bt;
    BatchBuf* mx = &bb[bt];
    int h = t2 / 37, k = t2 - h * 37;
    float acc = 0.f;
    if (k < 29) {
      int mybin = (k < 9) ? k : (k - 9);
      const int* bins = (k < 9) ? mx->Xa : mx->Xz;
      for (int s = 0; s < SEQ; ++s) {
        float at = mx->sc[s * 8 + h];
        acc += (bins[s] == mybin) ? at : 0.f;
      }
      if (k < 9) mx->attA[h * 9 + k] = acc; else mx->attZ[h * 20 + (k - 9)] = acc;
    } else if (k < 36) {
      int j = k - 29;
      for (int s = 0; s < SEQ; ++s) acc = fmaf(mx->sc[s * 8 + h], mx->Xo[s * 7 + j], acc);
      mx->oAcc[h * 7 + j] = acc;
    } else {
      for (int s = 0; s < SEQ; ++s) acc = fmaf(mx->sc[s * 8 + h], mx->pe[s], acc);
      mx->peAcc8[h] = acc;
    }
  }
  __syncthreads();

  // ---- phase 6b: reconstruct u[h][d] ----
  {
    float acc[NHEAD];
    #pragma unroll
    for (int h = 0; h < NHEAD; ++h) acc[h] = mb->peAcc8[h];
    if (tp < 64) {
      for (int a = 0; a < 9; ++a) {
        float ev = embA[a * 65 + tp];
        #pragma unroll
        for (int h = 0; h < NHEAD; ++h) acc[h] = fmaf(mb->attA[h * 9 + a], ev, acc[h]);
      }
    } else if (tp < 128) {
      int d = tp - 64;
      for (int z = 0; z < 20; ++z) {
        float ev = embZ[z * 65 + d];
        #pragma unroll
        for (int h = 0; h < NHEAD; ++h) acc[h] = fmaf(mb->attZ[h * 20 + z], ev, acc[h]);
      }
    } else {
      int kk = tp - 128;
      #pragma unroll
      for (int j = 0; j < 7; ++j) {
        float ov = l0w[kk * 7 + j];
        #pragma unroll
        for (int h = 0; h < NHEAD; ++h) acc[h] = fmaf(mb->oAcc[h * 7 + j], ov, acc[h]);
      }
      #pragma unroll
      for (int h = 0; h < NHEAD; ++h) acc[h] += l0b[kk];
    }
    #pragma unroll
    for (int h = 0; h < NHEAD; ++h) mb->sc[h * DIM + tp] = acc[h];
  }
  __syncthreads();

  // ---- phase 7: ao = Wv @ u + bv (rows of head k use u[k]) ----
  for (int k = 0; k < 8; ++k) {
    int r = wid + 32 * k;
    float4 x0 = *(const float4*)(sc0 + k * DIM + lane * 4);
    float4 x1 = *(const float4*)(sc1 + k * DIM + lane * 4);
    float u = rows4_dot<256>(qkv_w + (size_t)(2 * DIM) * DIM, r, lane, x0, x1);
    int rr, bsel;
    if (out_slot(lane, r, rr, bsel))
      (bsel ? bb[1].ao : bb[0].ao)[rr] = qkv_b[2 * DIM + rr] + u;
  }
  __syncthreads();

  // ---- phase 8: tv = srcl + attn_o(ao); h1 = LN1(tv) ----
  {
    float4 x0 = *(const float4*)(bb[0].ao + lane * 4);
    float4 x1 = *(const float4*)(bb[1].ao + lane * 4);
    for (int k = 0; k < 8; ++k) {
      int r = wid + 32 * k;
      float u = rows4_dot<256>(attn_o_w, r, lane, x0, x1);
      int rr, bsel;
      if (out_slot(lane, r, rr, bsel)) {
        float base = (bsel ? bb[1].srcl : bb[0].srcl)[rr] + attn_o_b[rr];
        (bsel ? bb[1].qv : bb[0].qv)[rr] = base + u;
      }
    }
  }
  __syncthreads();
  {
    float tv = mb->qv[tp];
    float mean = batch_sum(tv, red, wid, batch) * (1.0f / 256.0f);
    float dv = tv - mean;
    float var = batch_sum(dv * dv, red, wid, batch) * (1.0f / 256.0f);
    mb->h1[tp] = dv / sqrtf(var + 1e-5f) * ln1_g[tp] + ln1_b[tp];
  }
  __syncthreads();

  // ---- phase 9: ffb = relu(ff1 @ h1 + b) ----
  {
    float4 x0 = *(const float4*)(bb[0].h1 + lane * 4);
    float4 x1 = *(const float4*)(bb[1].h1 + lane * 4);
    for (int k = 0; k < 32; ++k) {
      int r = wid + 32 * k;
      float u = rows4_dot<256>(ff1_w, r, lane, x0, x1);
      int rr, bsel;
      if (out_slot(lane, r, rr, bsel))
        (bsel ? sc1 : sc0)[rr] = fmaxf(ff1_b[rr] + u, 0.f);
    }
  }
  __syncthreads();

  // ---- phase 10: tv = h1 + ff2 @ ffb + b; h2 = LN2(tv) ----
  for (int k = 0; k < 8; ++k) {
    int r = wid + 32 * k;
    float a0 = 0.f, a1 = 0.f, a2 = 0.f, a3 = 0.f, a4 = 0.f, a5 = 0.f, a6 = 0.f, a7 = 0.f;
    #pragma unroll
    for (int kc = 0; kc < 4; ++kc) {
      float4 x0 = *(const float4*)(sc0 + kc * 256 + lane * 4);
      float4 x1 = *(const float4*)(sc1 + kc * 256 + lane * 4);
      const float* wp = ff2_w + (size_t)r * DFF + kc * 256 + lane * 4;
      float4 w0 = *(const float4*)(wp);
      float4 w1 = *(const float4*)(wp + 8 * DFF);
      float4 w2 = *(const float4*)(wp + 16 * DFF);
      float4 w3 = *(const float4*)(wp + 24 * DFF);
      a0 += dot4f(w0, x0); a1 += dot4f(w0, x1);
      a2 += dot4f(w1, x0); a3 += dot4f(w1, x1);
      a4 += dot4f(w2, x0); a5 += dot4f(w2, x1);
      a6 += dot4f(w3, x0); a7 += dot4f(w3, x1);
    }
    float u = fold8(lane, a0, a1, a2, a3, a4, a5, a6, a7);
    int rr, bsel;
    if (out_slot(lane, r, rr, bsel)) {
      float base = (bsel ? bb[1].h1 : bb[0].h1)[rr] + ff2_b[rr];
      (bsel ? bb[1].qv : bb[0].qv)[rr] = base + u;
    }
  }
  __syncthreads();
  {
    float tv = mb->qv[tp];
    float mean = batch_sum(tv, red, wid, batch) * (1.0f / 256.0f);
    float dv = tv - mean;
    float var = batch_sum(dv * dv, red, wid, batch) * (1.0f / 256.0f);
    mb->h2[tp] = dv / sqrtf(var + 1e-5f) * ln2_g[tp] + ln2_b[tp];
  }
  __syncthreads();

  // ---- phase 11: xr = relu_w @ h2 + b ----
  {
    float4 x0 = *(const float4*)(bb[0].h2 + lane * 4);
    float4 x1 = *(const float4*)(bb[1].h2 + lane * 4);
    for (int k = 0; k < 8; ++k) {
      int r = wid + 32 * k;
      float u = rows4_dot<256>(relu_w, r, lane, x0, x1);
      int rr, bsel;
      if (out_slot(lane, r, rr, bsel))
        (bsel ? bb[1].xr : bb[0].xr)[rr] = relu_b[rr] + u;
    }
  }
  __syncthreads();

  // ---- phase 12: d1 = dT_w @ xr + b; dT = lindT . d1 + b ----
  {
    float4 x0 = *(const float4*)(bb[0].xr + lane * 4);
    float4 x1 = *(const float4*)(bb[1].xr + lane * 4);
    for (int k = 0; k < 8; ++k) {
      int r = wid + 32 * k;
      float u = rows4_dot<256>(dT_w, r, lane, x0, x1);
      int rr, bsel;
      if (out_slot(lane, r, rr, bsel))
        (bsel ? bb[1].h1 : bb[0].h1)[rr] = dT_b[rr] + u;   // h1 = d1
    }
  }
  __syncthreads();
  float dTv;
  {
    float v = lindT_w[tp] * mb->h1[tp];
    dTv = batch_sum(v, red, wid, batch) + lindT_b[0];
  }

  // ---- phase 13: zn path ----
  mb->znin[1 + tp] = mb->xr[tp];
  mb->fa[21 + tp] = mb->xr[tp];
  if (tp == 0) { mb->znin[0] = dTv; mb->fa[20] = dTv; }
  __syncthreads();
  float* z1_0 = sc0 + 1024; float* z1_1 = sc1 + 1024;
  for (int r0 = 2 * wid; r0 < 257; r0 += 16) {
    int r1 = r0 + 1;
    bool has2 = (r1 < 257);
    const float* wa = zn_w + (size_t)r0 * 257;
    const float* wb = zn_w + (size_t)r1 * 257;
    float pa0 = 0.f, pa1 = 0.f, pb0 = 0.f, pb1 = 0.f;
    for (int j = lane; j < 257; j += 64) {
      float xa = bb[0].znin[j], xb = bb[1].znin[j];
      float w0 = wa[j];
      pa0 = fmaf(w0, xa, pa0); pa1 = fmaf(w0, xb, pa1);
      if (has2) { float w1 = wb[j]; pb0 = fmaf(w1, xa, pb0); pb1 = fmaf(w1, xb, pb1); }
    }
    float u = fold4(lane, pa0, pa1, pb0, pb1);
    if ((lane & 15) == 0) {
      int g = lane >> 4;
      int rr = (g & 1) ? r1 : r0;
      if (rr < 257) ((g & 2) ? z1_1 : z1_0)[rr] = zn_b[rr] + u;
    }
  }
  __syncthreads();
  for (int r0 = 2 * wid; r0 < 20; r0 += 16) {
    int r1 = r0 + 1;
    const float* wa = linzn_w + (size_t)r0 * 257;
    const float* wb = linzn_w + (size_t)r1 * 257;
    float pa0 = 0.f, pa1 = 0.f, pb0 = 0.f, pb1 = 0.f;
    for (int j = lane; j < 257; j += 64) {
      float x0v = z1_0[j], x1v = z1_1[j];
      float w0 = wa[j], w1 = wb[j];
      pa0 = fmaf(w0, x0v, pa0); pa1 = fmaf(w0, x1v, pa1);
      pb0 = fmaf(w1, x0v, pb0); pb1 = fmaf(w1, x1v, pb1);
    }
    float u = fold4(lane, pa0, pa1, pb0, pb1);
    if ((lane & 15) == 0) {
      int g = lane >> 4;
      int rr = (g & 1) ? r1 : r0;
      if (rr < 20) {
        BatchBuf* mx = &bb[g >> 1];
        float v = linzn_b[rr] + u;
        mx->znv[rr] = v; mx->fa[rr] = v;
      }
    }
  }
  __syncthreads();

  // ---- phase 14: ac = linact @ act1 @ act0 @ fa ----
  float* a0_0 = sc0 + 1312; float* a0_1 = sc1 + 1312;
  for (int r0 = 2 * wid; r0 < 277; r0 += 16) {
    int r1 = r0 + 1;
    bool has2 = (r1 < 277);
    const float* wa = act0_w + (size_t)r0 * 277;
    const float* wb = act0_w + (size_t)r1 * 277;
    float pa0 = 0.f, pa1 = 0.f, pb0 = 0.f, pb1 = 0.f;
    for (int j = lane; j < 277; j += 64) {
      float xa = bb[0].fa[j], xb = bb[1].fa[j];
      float w0 = wa[j];
      pa0 = fmaf(w0, xa, pa0); pa1 = fmaf(w0, xb, pa1);
      if (has2) { float w1 = wb[j]; pb0 = fmaf(w1, xa, pb0); pb1 = fmaf(w1, xb, pb1); }
    }
    float u = fold4(lane, pa0, pa1, pb0, pb1);
    if ((lane & 15) == 0) {
      int g = lane >> 4;
      int rr = (g & 1) ? r1 : r0;
      if (rr < 277) ((g & 2) ? a0_1 : a0_0)[rr] = act0_b[rr] + u;
    }
  }
  __syncthreads();
  float* a1_0 = sc0 + 1024; float* a1_1 = sc1 + 1024;  // z1 dead
  for (int r0 = 2 * wid; r0 < 277; r0 += 16) {
    int r1 = r0 + 1;
    bool has2 = (r1 < 277);
    const float* wa = act1_w + (size_t)r0 * 277;
    const float* wb = act1_w + (size_t)r1 * 277;
    float pa0 = 0.f, pa1 = 0.f, pb0 = 0.f, pb1 = 0.f;
    for (int j = lane; j < 277; j += 64) {
      float xa = a0_0[j], xb = a0_1[j];
      float w0 = wa[j];
      pa0 = fmaf(w0, xa, pa0); pa1 = fmaf(w0, xb, pa1);
      if (has2) { float w1 = wb[j]; pb0 = fmaf(w1, xa, pb0); pb1 = fmaf(w1, xb, pb1); }
    }
    float u = fold4(lane, pa0, pa1, pb0, pb1);
    if ((lane & 15) == 0) {
      int g = lane >> 4;
      int rr = (g & 1) ? r1 : r0;
      if (rr < 277) ((g & 2) ? a1_1 : a1_0)[rr] = act1_b[rr] + u;
    }
  }
  __syncthreads();

  // ---- phase 15: outputs ----
  for (int r = wid; r < 5; r += NW) {
    const float* wr = linact_w + (size_t)r * 277;
    float p0 = 0.f, p1 = 0.f;
    for (int j = lane; j < 277; j += 64) {
      float w = wr[j];
      p0 = fmaf(w, a1_0[j], p0);
      p1 = fmaf(w, a1_1[j], p1);
    }
    p0 = wave_allred(p0); p1 = wave_allred(p1);
    if (lane == 0) {
      out[(2 * blockIdx.x)     * 26 + 21 + r] = linact_b[r] + p0;
      out[(2 * blockIdx.x + 1) * 26 + 21 + r] = linact_b[r] + p1;
    }
  }
  if (tp == 0) out[b * 26] = dTv;
  if (tp < 20) out[b * 26 + 1 + tp] = mb->znv[tp];
}

// ---------- launcher ----------

extern "C" void kernel_launch(void* const* d_in, const int* in_sizes, int n_in,
                              void* d_out, int out_size, void* d_ws, size_t ws_size,
                              hipStream_t stream) {
  (void)in_sizes; (void)n_in; (void)d_ws; (void)ws_size; (void)out_size;
  const int*   X        = (const int*)  d_in[0];
  const float* emb_act  = (const float*)d_in[1];
  const float* emb_zone = (const float*)d_in[2];
  const float* lin0_w   = (const float*)d_in[3];
  const float* lin0_b   = (const float*)d_in[4];
  const float* qkv_w    = (const float*)d_in[5];
  const float* qkv_b    = (const float*)d_in[6];
  const float* attn_o_w = (const float*)d_in[7];
  const float* attn_o_b = (const float*)d_in[8];
  const float* ln1_g    = (const float*)d_in[9];
  const float* ln1_b    = (const float*)d_in[10];
  const float* ff1_w    = (const float*)d_in[11];
  const float* ff1_b    = (const float*)d_in[12];
  const float* ff2_w    = (const float*)d_in[13];
  const float* ff2_b    = (const float*)d_in[14];
  const float* ln2_g    = (const float*)d_in[15];
  const float* ln2_b    = (const float*)d_in[16];
  const float* relu_w   = (const float*)d_in[17];
  const float* relu_b   = (const float*)d_in[18];
  const float* dT_w     = (const float*)d_in[19];
  const float* dT_b     = (const float*)d_in[20];
  const float* lindT_w  = (const float*)d_in[21];
  const float* lindT_b  = (const float*)d_in[22];
  const float* zn_w     = (const float*)d_in[23];
  const float* zn_b     = (const float*)d_in[24];
  const float* linzn_w  = (const float*)d_in[25];
  const float* linzn_b  = (const float*)d_in[26];
  const float* act0_w   = (const float*)d_in[27];
  const float* act0_b   = (const float*)d_in[28];
  const float* act1_w   = (const float*)d_in[29];
  const float* act1_b   = (const float*)d_in[30];
  const float* linact_w = (const float*)d_in[31];
  const float* linact_b = (const float*)d_in[32];
  float* out = (float*)d_out;

  nmstpp_fused<<<dim3(BATCH / 2), dim3(NT), 0, stream>>>(
      X, emb_act, emb_zone, lin0_w, lin0_b, qkv_w, qkv_b, attn_o_w, attn_o_b,
      ln1_g, ln1_b, ff1_w, ff1_b, ff2_w, ff2_b, ln2_g, ln2_b,
      relu_w, relu_b, dT_w, dT_b, lindT_w, lindT_b, zn_w, zn_b,
      linzn_w, linzn_b, act0_w, act0_b, act1_w, act1_b, linact_w, linact_b,
      out);
}